// Round 9
// baseline (172.964 us; speedup 1.0000x reference)
//
#include <hip/hip_runtime.h>
#include <hip/hip_bf16.h>

// DeepFM on MI355X. B=16384, NF=50, K=16, V=1e6, H=400, d=800.
// index = repeat(arange(B), NF) -> sample s owns rows [s*50, s*50+50).
//
// Timed-region: ~121us = 3x 256-MiB harness poison fills (fixed floor)
// + prep + fused.  R8 post-mortem: LDS-read-count lever falsified (72->56
// reads/plane = no change).  R9 removes the x round-trip entirely:
//
//   k1 prep:  transpose ONLY (W0->W0t [512][800], W1->W1t [512][416],
//             bf16 n-major zero-padded).  ~3us.
//   k2 fused: one block / 64-sample panel, 512 threads (8 waves).
//     prologue: prestage B plane 0; BULK GATHER: 8 threads/sample, each
//       thread 25x float4 embedding loads (75 VMEM deep queue, BW-bound,
//       NOT R1's in-K-loop latency chain); fs (first+second order) fully
//       in-register via 8-lane shuffle groups -> fsl LDS; bf16 A-panel
//       (64x800 = 100 KB) written to LDS in MFMA-swizzled layout
//       (write-side swizzle == read-side qsw, slot algebra verified).
//     phase 1: h0 = relu(panel @ W0t + b0): A from resident panel, B
//       DMA-staged 28 chunks/plane, 2-buffer depth-1 (VMCNT(0) + ONE
//       bar/plane; stage(p+1) after bar is race-free: buf (p+1)&1 last
//       read by compute(p-1), done at bar(p)).
//     h0 -> LDS [64][424] (overwrites dead panel region, barrier-guarded).
//     phase 2: relu(h0 @ W1t + b1) . W2, same loop over 13 planes.
//     epilogue: cross-wave reduce + fsl + sigmoid -> out.
//   Wave geometry: waves 0..6 compute 64x64 tiles (cols 0..447; rows
//   400..511 of W0t/W1t are zeros so padded cols are harmless and h0
//   cols [400,416) get written 0 by wave 6 j=1); wave 7 stages+gathers
//   only (static wave-uniform branch -> no dynamic acc indexing).
//   LDS: panel 100K | B 2x28K | red 2K | fsl 256B = 158.25 KB.

#define BATCH 16384
#define NFLD  50
#define EK    16
#define DDIM  800   // NF*K (= gemm1 K, 25 planes)
#define HDIM  400
#define HPAD  416   // gemm2 K (13 planes)
#define NPAD  512   // W0t/W1t allocated rows

#define TB_W0 400            // 25 k-tiles x 16 n-tiles
#define TB_W1 208            // 13 k-tiles x 16 n-tiles
#define TBLK  (TB_W0 + TB_W1)

#define MROWS 64
#define P1    (DDIM / 32)    // 25
#define P2    (HPAD / 32)    // 13
#define H0S   424            // h0 LDS stride (bf16)

#define BOFF   102400        // B staging after 100 KB panel
#define BBUF   28672         // 28 chunks x 1 KB
#define REDOFF (BOFF + 2 * BBUF)        // 159744
#define FSLOFF (REDOFF + 2048)          // 161792
#define LDSSZ  (FSLOFF + 256)           // 162048

#define VMCNT(N) asm volatile("s_waitcnt vmcnt(" #N ")" ::: "memory")

typedef __attribute__((ext_vector_type(8))) __bf16 bf16x8;
typedef __attribute__((ext_vector_type(4))) float  f32x4;

typedef const __attribute__((address_space(1))) unsigned int* gas_u32p;
typedef __attribute__((address_space(3))) unsigned int*       las_u32p;

__device__ __forceinline__ void gld_lds16(const void* g, void* l) {
    __builtin_amdgcn_global_load_lds((gas_u32p)g, (las_u32p)l, 16, 0, 0);
}

__device__ __forceinline__ void bar() {
    __builtin_amdgcn_sched_barrier(0);
    __builtin_amdgcn_s_barrier();
    __builtin_amdgcn_sched_barrier(0);
}

// ---------------- k1: weight transpose only ----------------
__global__ __launch_bounds__(256) void prep_kernel(
    const float* __restrict__ W0, const float* __restrict__ W1,
    __hip_bfloat16* __restrict__ W0t, __hip_bfloat16* __restrict__ W1t)
{
    const int bid = blockIdx.x;
    const int which = bid >= TB_W0;
    const int i  = which ? bid - TB_W0 : bid;
    const int nx = which ? 13 : 25;
    const int bx = i % nx, by = i / nx;
    const float* src = which ? W1 : W0;
    __hip_bfloat16* dst = which ? W1t : W0t;
    const int srcK = which ? HDIM : DDIM;
    const int dstCols = which ? HPAD : DDIM;

    __shared__ float tile[32][33];
    const int tx = threadIdx.x & 31, ty = threadIdx.x >> 5;
    const int k0 = bx * 32, n0 = by * 32;
#pragma unroll
    for (int r = 0; r < 4; ++r) {
        int k = k0 + ty + r * 8;
        int n = n0 + tx;
        float v = (k < srcK && n < HDIM) ? src[(long)k * HDIM + n] : 0.f;
        tile[ty + r * 8][tx] = v;
    }
    __syncthreads();
#pragma unroll
    for (int r = 0; r < 4; ++r) {
        int n = n0 + ty + r * 8;   // dst row
        int k = k0 + tx;           // dst col
        if (k < dstCols)
            dst[(long)n * dstCols + k] = __float2bfloat16(tile[tx][ty + r * 8]);
    }
}

// ---------------- k2: gather + GEMM1 -> LDS h0 -> GEMM2 -> final ----------------
__global__ __launch_bounds__(512, 2) void fused_mlp_kernel(
    const int* __restrict__ feats, const float* __restrict__ values,
    const float* __restrict__ biasp, const float* __restrict__ weights,
    const float* __restrict__ embedding,
    const __hip_bfloat16* __restrict__ W0t, const __hip_bfloat16* __restrict__ W1t,
    const float* __restrict__ b0p, const float* __restrict__ b1p,
    const float* __restrict__ W2, const float* __restrict__ b2p,
    float* __restrict__ out)
{
    __shared__ __align__(16) char lds[LDSSZ];
    __hip_bfloat16* h0p = (__hip_bfloat16*)lds;            // overwrites panel
    float*          red = (float*)(lds + REDOFF);
    float*          fsl = (float*)(lds + FSLOFF);

    const int tid  = threadIdx.x;
    const int wave = tid >> 6, lane = tid & 63;
    const int l16  = lane & 15, quad = lane >> 4;
    const int m0 = blockIdx.x * MROWS;

    const int rl  = lane >> 2;
    const int swc = ((lane & 3) ^ ((lane >> 3) & 3)) * 8;   // DMA source swizzle
    const int qsw = (quad ^ ((l16 >> 1) & 3)) * 8;          // fragment read swizzle

    // ---- B staging: 28 chunks/plane; waves 0..3 x4, waves 4..7 x3 ----
    auto stageB = [&](const __hip_bfloat16* Bt, int ldb, int p, int b) {
        const int k0  = p * 32;
        const int nst = (wave < 4) ? 4 : 3;
        const int st0 = (wave < 4) ? wave * 4 : 16 + (wave - 4) * 3;
#pragma unroll
        for (int c = 0; c < 4; ++c) {
            if (c < nst) {                               // wave-uniform
                const int ch = st0 + c;
                gld_lds16(Bt + (long)(ch * 16 + rl) * ldb + k0 + swc,
                          lds + BOFF + b * BBUF + ch * 1024 + lane * 16);
            }
        }
    };

    // prestage phase-1 plane 0 so its DMA hides under the gather
    stageB(W0t, DDIM, 0, 0);

    // ---- bulk gather: 8 threads/sample; fs in-register; panel -> LDS ----
    {
        const int s   = tid >> 3;        // 0..63
        const int sub = tid & 7;
        const int cq  = sub & 3;         // dim quarter (4 floats)
        const int jh  = sub >> 2;        // row half (25 rows)
        const long sb = (long)(m0 + s) * NFLD;
        const int pr = s & 15, pg = s >> 4;
        const int pbase = pg * 1024 + pr * 64 + (cq & 1) * 8;
        const int sxor  = (pr >> 1) & 3;

        f32x4 s1v = {0.f, 0.f, 0.f, 0.f}, s2v = {0.f, 0.f, 0.f, 0.f};
        float wsum = 0.f;
#pragma unroll
        for (int g = 0; g < 5; ++g) {
            int ff[5]; float vv[5]; float4 ee[5];
#pragma unroll
            for (int k = 0; k < 5; ++k) ff[k] = feats[sb + jh * 25 + g * 5 + k];
#pragma unroll
            for (int k = 0; k < 5; ++k) vv[k] = values[sb + jh * 25 + g * 5 + k];
#pragma unroll
            for (int k = 0; k < 5; ++k)
                ee[k] = *(const float4*)(embedding + (long)ff[k] * EK + cq * 4);
#pragma unroll
            for (int k = 0; k < 5; ++k) {
                const int j = jh * 25 + g * 5 + k;
                f32x4 ef = {ee[k].x, ee[k].y, ee[k].z, ee[k].w};
                f32x4 ev = ef * vv[k];
                s1v += ev;
                s2v += ev * ev;
                if (cq == 0) wsum += weights[ff[k]] * vv[k];
                __hip_bfloat16 pk[4] = {
                    __float2bfloat16(ee[k].x), __float2bfloat16(ee[k].y),
                    __float2bfloat16(ee[k].z), __float2bfloat16(ee[k].w)};
                const int slot = (j & 1) * 2 + (cq >> 1);
                *(uint2*)(lds + (j >> 1) * 4096 + pbase + (slot ^ sxor) * 16) =
                    *(uint2*)pk;
            }
        }
        // reduce row-halves (xor 4), then quarters (xor 1,2) within 8 lanes
        s1v.x += __shfl_xor(s1v.x, 4); s1v.y += __shfl_xor(s1v.y, 4);
        s1v.z += __shfl_xor(s1v.z, 4); s1v.w += __shfl_xor(s1v.w, 4);
        s2v.x += __shfl_xor(s2v.x, 4); s2v.y += __shfl_xor(s2v.y, 4);
        s2v.z += __shfl_xor(s2v.z, 4); s2v.w += __shfl_xor(s2v.w, 4);
        wsum  += __shfl_xor(wsum, 4);
        float tq = (s1v.x * s1v.x - s2v.x) + (s1v.y * s1v.y - s2v.y)
                 + (s1v.z * s1v.z - s2v.z) + (s1v.w * s1v.w - s2v.w);
        tq += __shfl_xor(tq, 1); tq += __shfl_xor(tq, 2);
        if (sub == 0) fsl[s] = wsum + 0.5f * tq + biasp[0];
    }
    asm volatile("s_waitcnt lgkmcnt(0)" ::: "memory");   // panel + fsl written

    const float b0 = b0p[0];
    const float b1 = b1p[0];

    // ---- phase 1: 25 planes, 2-buffer depth-1, one bar/plane ----
    f32x4 acc[4][4] = {};
    auto compute1 = [&](int p, int b) {
        const __hip_bfloat16* pan = (const __hip_bfloat16*)lds;
        const __hip_bfloat16* sB  = (const __hip_bfloat16*)(lds + BOFF + b * BBUF);
        bf16x8 af[4], bfr[4];
#pragma unroll
        for (int i = 0; i < 4; ++i)
            af[i] = *(const bf16x8*)&pan[p * 2048 + i * 512 + l16 * 32 + qsw];
#pragma unroll
        for (int j = 0; j < 4; ++j)
            bfr[j] = *(const bf16x8*)&sB[(wave * 4 + j) * 512 + l16 * 32 + qsw];
        __builtin_amdgcn_s_setprio(1);
#pragma unroll
        for (int i = 0; i < 4; ++i)
#pragma unroll
            for (int j = 0; j < 4; ++j)
                acc[i][j] = __builtin_amdgcn_mfma_f32_16x16x32_bf16(
                    af[i], bfr[j], acc[i][j], 0, 0, 0);
        __builtin_amdgcn_s_setprio(0);
    };

    for (int p = 0; p < P1; ++p) {
        VMCNT(0);
        bar();                          // plane p resident for ALL waves
        if (p + 1 < P1) stageB(W0t, DDIM, p + 1, (p + 1) & 1);
        if (wave < 7) compute1(p, p & 1);
    }
    bar();                              // all panel + buf reads done

    stageB(W1t, HPAD, 0, 0);            // phase-2 plane 0 (buf0 free now)

    // ---- h0 -> LDS [64][H0S]: relu+b0; wave6 j=1 writes cols[400,416)=0 ----
    if (wave < 7) {
#pragma unroll
        for (int i = 0; i < 4; ++i)
#pragma unroll
            for (int j = 0; j < 4; ++j) {
                const int col = wave * 64 + j * 16 + l16;
                if (col < HPAD) {
#pragma unroll
                    for (int r = 0; r < 4; ++r) {
                        const int row = i * 16 + quad * 4 + r;
                        float v = acc[i][j][r] + b0;
                        v = v > 0.f ? v : 0.f;
                        if (col >= HDIM) v = 0.f;
                        h0p[row * H0S + col] = __float2bfloat16(v);
                    }
                }
            }
    }
    asm volatile("s_waitcnt lgkmcnt(0)" ::: "memory");
    bar();                              // h0p published; plane-0 DMA in flight

    // ---- phase 2: 13 planes, same loop ----
    f32x4 acc2[4][4] = {};
    auto compute2 = [&](int p, int b) {
        const __hip_bfloat16* sB = (const __hip_bfloat16*)(lds + BOFF + b * BBUF);
        bf16x8 af[4], bfr[4];
#pragma unroll
        for (int i = 0; i < 4; ++i)
            af[i] = *(const bf16x8*)&h0p[(i * 16 + l16) * H0S + p * 32 + quad * 8];
#pragma unroll
        for (int j = 0; j < 4; ++j)
            bfr[j] = *(const bf16x8*)&sB[(wave * 4 + j) * 512 + l16 * 32 + qsw];
        __builtin_amdgcn_s_setprio(1);
#pragma unroll
        for (int i = 0; i < 4; ++i)
#pragma unroll
            for (int j = 0; j < 4; ++j)
                acc2[i][j] = __builtin_amdgcn_mfma_f32_16x16x32_bf16(
                    af[i], bfr[j], acc2[i][j], 0, 0, 0);
        __builtin_amdgcn_s_setprio(0);
    };

    for (int p = 0; p < P2; ++p) {
        VMCNT(0);
        bar();
        if (p + 1 < P2) stageB(W1t, HPAD, p + 1, (p + 1) & 1);
        if (wave < 7) compute2(p, p & 1);
    }

    // ---- epilogue: relu(acc2+b1).W2, lane reduce, cross-wave, sigmoid ----
    if (tid < MROWS) red[tid * 8 + 7] = 0.f;            // wave-7 slot
    if (wave < 7) {
        float w2v[4];
#pragma unroll
        for (int j = 0; j < 4; ++j) {
            const int col = wave * 64 + j * 16 + l16;
            w2v[j] = (col < HDIM) ? W2[col] : 0.f;
        }
#pragma unroll
        for (int i = 0; i < 4; ++i)
#pragma unroll
            for (int r = 0; r < 4; ++r) {
                float ps = 0.f;
#pragma unroll
                for (int j = 0; j < 4; ++j) {
                    float v = acc2[i][j][r] + b1;
                    v = v > 0.f ? v : 0.f;
                    ps += v * w2v[j];
                }
                ps += __shfl_xor(ps, 1); ps += __shfl_xor(ps, 2);
                ps += __shfl_xor(ps, 4); ps += __shfl_xor(ps, 8);
                if (l16 == 0)
                    red[(i * 16 + quad * 4 + r) * 8 + wave] = ps;
            }
    }
    __syncthreads();

    if (tid < MROWS) {
        const float4 r0 = *(const float4*)&red[tid * 8];
        const float4 r1 = *(const float4*)&red[tid * 8 + 4];
        const float sm = ((r0.x + r0.y) + (r0.z + r0.w))
                       + ((r1.x + r1.y) + (r1.z + r1.w));
        float hv = sm + b2p[0];
        hv = hv > 0.f ? hv : 0.f;
        const float z = fsl[tid] + hv;
        out[m0 + tid] = 1.f / (1.f + __expf(-z));
    }
}

extern "C" void kernel_launch(void* const* d_in, const int* in_sizes, int n_in,
                              void* d_out, int out_size, void* d_ws, size_t ws_size,
                              hipStream_t stream)
{
    const int*   feats     = (const int*)d_in[1];
    const float* values    = (const float*)d_in[2];
    const float* bias      = (const float*)d_in[3];
    const float* weights   = (const float*)d_in[4];
    const float* embedding = (const float*)d_in[5];
    const float* W0 = (const float*)d_in[6];
    const float* b0 = (const float*)d_in[7];
    const float* W1 = (const float*)d_in[8];
    const float* b1 = (const float*)d_in[9];
    const float* W2 = (const float*)d_in[10];
    const float* b2 = (const float*)d_in[11];

    char* ws = (char*)d_ws;
    size_t off = 0;
    auto alloc = [&](size_t bytes) {
        void* p = ws + off;
        off += (bytes + 255) & ~(size_t)255;
        return p;
    };
    __hip_bfloat16* W0t = (__hip_bfloat16*)alloc((size_t)NPAD * DDIM * 2);
    __hip_bfloat16* W1t = (__hip_bfloat16*)alloc((size_t)NPAD * HPAD * 2);
    (void)ws_size; (void)in_sizes; (void)n_in; (void)out_size;

    prep_kernel<<<dim3(TBLK), 256, 0, stream>>>(W0, W1, W0t, W1t);
    fused_mlp_kernel<<<dim3(BATCH / MROWS), 512, 0, stream>>>(
        feats, values, bias, weights, embedding,
        W0t, W1t, b0, b1, W2, b2, (float*)d_out);
}

// Round 10
// 165.713 us; speedup vs baseline: 1.0438x; 1.0438x over previous
//
#include <hip/hip_runtime.h>
#include <hip/hip_bf16.h>

// DeepFM on MI355X. B=16384, NF=50, K=16, V=1e6, H=400, d=800.
// index = repeat(arange(B), NF) -> sample s owns rows [s*50, s*50+50).
//
// Timed-region decomposition: ~121us = 3x 256-MiB harness poison fills
// (fixed floor) + prep ~14us + fused ~31us.  This is the R6 configuration
// (best measured: 166.1us), reverted to after R7/R8/R9 falsified the
// remaining structural alternatives:
//   R1/R9: gather inside fused kernel  -> latency/overfetch-bound (57/77us)
//   R2:    stage-then-drain 2-bar/plane -> m233 drain tax (58us)
//   R5:    BK=64 pair buffers           -> LDS-infeasible (128K+53K > 160K)
//   R7:    direct-global B (no LDS)     -> L2-scatter latency-bound (+5us)
//   R8:    7-wave 1Mx7N geometry        -> null (LDS-read count not binding)
//
//   k1 prep:  blocks 0..607 transpose W0->W0t [512][800], W1->W1t [512][416]
//             (bf16, n-major, zero-padded); blocks 608..: per-sample first+
//             second order -> fs, emb -> x bf16 [16384][800] (high-occupancy
//             gather, 16 row-loads in flight/wave).
//   k2 fused: one block per 64-sample panel, 512 threads (8 waves, 2Mx4N):
//             phase 1: h0 = relu(x @ W0t + b0) -> LDS [64][424] bf16,
//               25 BK=32 planes, 3-deep rotating buffers, ONE raw barrier
//               per plane, counted VMCNT(4) (T3/T4: 2 planes stay in
//               flight across barriers; never vmcnt(0) in loop).
//             phase 2: h1 = relu(h0 @ W1t + b1) . W2, 13 planes, same
//               schedule; out = sigmoid(fs + relu(sum + b2)).
//             T2 both-sides swizzle (DMA source slot ^ (row>>1)&3, read
//             slot ^ (l16>>1)&3) -> 2-way LDS reads.  T5 setprio on MFMA.

#define BATCH 16384
#define NFLD  50
#define EK    16
#define DDIM  800   // NF*K  (= gemm1 K, exact, 25 planes)
#define HDIM  400
#define HPAD  416   // gemm2 K (13 planes)
#define NPAD  512   // W0t/W1t allocated rows

#define TB_W0 400            // 25 k-tiles x 16 n-tiles for W0 transpose
#define TB_W1 208            // 13 k-tiles x 16 n-tiles for W1 transpose
#define TBLK  (TB_W0 + TB_W1)
#define GBLK  (BATCH / 16)

#define MROWS 64             // samples per fused block
#define NCOLS 448            // gemm n-cols computed (28x16)
#define WCOLS 112            // n-cols per waveN
#define NFRAG 7              // 16-col frags per wave
#define P1    (DDIM / 32)    // 25 K-planes, phase 1
#define P2    (HPAD / 32)    // 13 K-planes, phase 2
#define H0S   424            // h0 LDS stride: 848B rows -> 2-way af reads

// LDS byte offsets
#define PH1B(b) ((b) * 32768)          // 3 plane buffers (A 4KB + B 28KB)
#define PH2B(b) ((b) * 28672)          // 3 plane buffers (B only, 28KB)
#define H0OFF   98304                  // h0p: 64*424*2 = 54272 B
#define REDOFF  152576                 // red: 64*4*4 = 1024 B
#define LDSSZ   153600                 // 150 KB

#define VMCNT(N) asm volatile("s_waitcnt vmcnt(" #N ")" ::: "memory")

typedef __attribute__((ext_vector_type(8))) __bf16 bf16x8;
typedef __attribute__((ext_vector_type(4))) float  f32x4;

typedef const __attribute__((address_space(1))) unsigned int* gas_u32p;
typedef __attribute__((address_space(3))) unsigned int*       las_u32p;

__device__ __forceinline__ void gld_lds16(const void* g, void* l) {
    __builtin_amdgcn_global_load_lds((gas_u32p)g, (las_u32p)l, 16, 0, 0);
}

__device__ __forceinline__ void bar() {
    // raw barrier (no vmcnt drain) with compile-time fences (rule #18/#21)
    __builtin_amdgcn_sched_barrier(0);
    __builtin_amdgcn_s_barrier();
    __builtin_amdgcn_sched_barrier(0);
}

// ---------------- k1: transpose (blocks < TBLK) + gather ----------------
__global__ __launch_bounds__(256) void prep_kernel(
    const float* __restrict__ W0, const float* __restrict__ W1,
    __hip_bfloat16* __restrict__ W0t, __hip_bfloat16* __restrict__ W1t,
    const int* __restrict__ feats, const float* __restrict__ values,
    const float* __restrict__ biasp, const float* __restrict__ weights,
    const float* __restrict__ embedding,
    float* __restrict__ fs, __hip_bfloat16* __restrict__ x)
{
    const int bid = blockIdx.x;
    if (bid < TBLK) {
        const int which = bid >= TB_W0;
        const int i  = which ? bid - TB_W0 : bid;
        const int nx = which ? 13 : 25;                  // k-tiles
        const int bx = i % nx, by = i / nx;
        const float* src = which ? W1 : W0;
        __hip_bfloat16* dst = which ? W1t : W0t;
        const int srcK = which ? HDIM : DDIM;            // source rows (k)
        const int dstCols = which ? HPAD : DDIM;

        __shared__ float tile[32][33];
        const int tx = threadIdx.x & 31, ty = threadIdx.x >> 5;
        const int k0 = bx * 32, n0 = by * 32;
#pragma unroll
        for (int r = 0; r < 4; ++r) {
            int k = k0 + ty + r * 8;
            int n = n0 + tx;
            float v = (k < srcK && n < HDIM) ? src[(long)k * HDIM + n] : 0.f;
            tile[ty + r * 8][tx] = v;
        }
        __syncthreads();
#pragma unroll
        for (int r = 0; r < 4; ++r) {
            int n = n0 + ty + r * 8;   // dst row
            int k = k0 + tx;           // dst col
            if (k < dstCols)
                dst[(long)n * dstCols + k] = __float2bfloat16(tile[tx][ty + r * 8]);
        }
        return;
    }

    const int wave = threadIdx.x >> 6;
    const int lane = threadIdx.x & 63;
    const int r    = lane >> 2, c = lane & 3;
    const int sbase = (bid - TBLK) * 16 + wave * 4;

    int   f[4] = {0, 0, 0, 0};
    float v[4] = {0.f, 0.f, 0.f, 0.f};
    float wsum[4] = {0.f, 0.f, 0.f, 0.f};
#pragma unroll
    for (int q = 0; q < 4; ++q) {
        const long base = (long)(sbase + q) * NFLD;
        if (lane < NFLD) {
            f[q] = feats[base + lane];
            v[q] = values[base + lane];
            wsum[q] = weights[f[q]] * v[q];
        }
    }

    int   fj[4][4]; float vj[4][4];
#pragma unroll
    for (int q = 0; q < 4; ++q)
#pragma unroll
        for (int p = 0; p < 4; ++p) {
            const int j = p * 16 + r;
            if (p < 3 || r < 2) {
                fj[q][p] = __shfl(f[q], j);
                vj[q][p] = __shfl(v[q], j);
            }
        }
    float4 e[4][4];
#pragma unroll
    for (int q = 0; q < 4; ++q)
#pragma unroll
        for (int p = 0; p < 4; ++p)
            if (p < 3 || r < 2)
                e[q][p] = *(const float4*)(embedding + (long)fj[q][p] * EK + c * 4);

#pragma unroll
    for (int q = 0; q < 4; ++q) {
        const int s = sbase + q;
        f32x4 s1 = {0.f, 0.f, 0.f, 0.f}, s2 = {0.f, 0.f, 0.f, 0.f};
#pragma unroll
        for (int p = 0; p < 4; ++p) {
            const int j = p * 16 + r;
            if (p < 3 || r < 2) {
                f32x4 ef = {e[q][p].x, e[q][p].y, e[q][p].z, e[q][p].w};
                f32x4 ev = ef * vj[q][p];
                s1 += ev;
                s2 += ev * ev;
                __hip_bfloat16 pk[4] = {
                    __float2bfloat16(e[q][p].x), __float2bfloat16(e[q][p].y),
                    __float2bfloat16(e[q][p].z), __float2bfloat16(e[q][p].w)};
                *(uint2*)&x[(long)s * DDIM + j * EK + c * 4] = *(uint2*)pk;
            }
        }
#pragma unroll
        for (int m = 4; m <= 32; m <<= 1) {
            s1.x += __shfl_xor(s1.x, m); s1.y += __shfl_xor(s1.y, m);
            s1.z += __shfl_xor(s1.z, m); s1.w += __shfl_xor(s1.w, m);
            s2.x += __shfl_xor(s2.x, m); s2.y += __shfl_xor(s2.y, m);
            s2.z += __shfl_xor(s2.z, m); s2.w += __shfl_xor(s2.w, m);
        }
        float t = (s1.x * s1.x - s2.x) + (s1.y * s1.y - s2.y)
                + (s1.z * s1.z - s2.z) + (s1.w * s1.w - s2.w);
        t += __shfl_xor(t, 1); t += __shfl_xor(t, 2);
        float w = wsum[q];
        w += __shfl_xor(w, 1);  w += __shfl_xor(w, 2);
        w += __shfl_xor(w, 4);  w += __shfl_xor(w, 8);
        w += __shfl_xor(w, 16); w += __shfl_xor(w, 32);
        if (lane == 0) fs[s] = w + 0.5f * t + biasp[0];
    }
}

// ---------------- k2: fused GEMM1 -> LDS h0 -> GEMM2 -> final ----------------
__global__ __launch_bounds__(512, 2) void fused_mlp_kernel(
    const __hip_bfloat16* __restrict__ x,
    const __hip_bfloat16* __restrict__ W0t, const __hip_bfloat16* __restrict__ W1t,
    const float* __restrict__ b0p, const float* __restrict__ b1p,
    const float* __restrict__ W2, const float* __restrict__ b2p,
    const float* __restrict__ fs, float* __restrict__ out)
{
    __shared__ __align__(16) char lds[LDSSZ];
    __hip_bfloat16* h0p = (__hip_bfloat16*)(lds + H0OFF);
    float*          red = (float*)(lds + REDOFF);

    const int tid  = threadIdx.x;
    const int wave = tid >> 6, lane = tid & 63;
    const int l16  = lane & 15, quad = lane >> 4;
    const int waveM = wave & 1, waveN = wave >> 1;
    const int m0 = blockIdx.x * MROWS;

    // staging lane geometry: chunk = 16 rows x 32 cols (1 KB);
    // lane -> row lane>>2, 16B slot lane&3; SOURCE slot pre-swizzled (rule #21)
    const int rl  = lane >> 2;
    const int swc = ((lane & 3) ^ ((lane >> 3) & 3)) * 8;   // = slot ^ ((row>>1)&3)
    // fragment-read slot swizzle: logical slot `quad` lives at quad ^ ((l16>>1)&3)
    const int qsw = (quad ^ ((l16 >> 1) & 3)) * 8;

    const float b0 = b0p[0];
    const float b1 = b1p[0];

    // ---- phase-1 staging: 1 plane = 32 chunks (A: 0..3 x-rows, B: 4..31
    // W0t rows), 4 chunks per wave ----
    auto stage1 = [&](int p, int b) {
        const int k0 = p * 32;
        char* dst = lds + PH1B(b);
#pragma unroll
        for (int c = 0; c < 4; ++c) {
            const int idx = wave * 4 + c;            // wave-uniform
            const __hip_bfloat16* src = (idx < 4)
                ? x   + (long)(m0 + idx * 16 + rl) * DDIM + k0 + swc
                : W0t + (long)((idx - 4) * 16 + rl) * DDIM + k0 + swc;
            gld_lds16(src, dst + idx * 1024 + lane * 16);
        }
    };

    f32x4 acc[2][NFRAG] = {};
    auto compute1 = [&](int b) {
        const __hip_bfloat16* s = (const __hip_bfloat16*)(lds + PH1B(b));
        bf16x8 af[2], bfr[NFRAG];
#pragma unroll
        for (int i = 0; i < 2; ++i)
            af[i] = *(const bf16x8*)&s[(waveM * 2 + i) * 512 + l16 * 32 + qsw];
#pragma unroll
        for (int j = 0; j < NFRAG; ++j)
            bfr[j] = *(const bf16x8*)&s[(4 + waveN * NFRAG + j) * 512 + l16 * 32 + qsw];
        __builtin_amdgcn_s_setprio(1);
#pragma unroll
        for (int i = 0; i < 2; ++i)
#pragma unroll
            for (int j = 0; j < NFRAG; ++j)
                acc[i][j] = __builtin_amdgcn_mfma_f32_16x16x32_bf16(
                    af[i], bfr[j], acc[i][j], 0, 0, 0);
        __builtin_amdgcn_s_setprio(0);
    };

    // ---- phase 1: 25 planes, 3-deep, ONE barrier per plane ----
    // invariant at bar(p): plane p landed (VMCNT(4), 2 planes in flight);
    // all waves finished compute(p-1) -> staging buf (p+2)%3 == (p-1)%3
    // after the bar is race-free.
    stage1(0, 0);
    stage1(1, 1);
    for (int p = 0; p < P1; ++p) {
        if (p + 1 < P1) { VMCNT(4); } else { VMCNT(0); }
        bar();
        if (p + 2 < P1) stage1(p + 2, (p + 2) % 3);
        compute1(p % 3);
    }
    bar();   // all compute1 ds_reads done before phase-2 staging overwrites

    // prologue for phase 2: issue planes 0,1 ASAP (overlap with h0p writes)
    auto stage2 = [&](int p, int b) {
        if (wave < 7) {
            const int k0 = p * 32;
#pragma unroll
            for (int c = 0; c < 4; ++c) {
                const int ch = wave * 4 + c;         // 0..27, wave-uniform
                gld_lds16(W1t + (long)(ch * 16 + rl) * HPAD + k0 + swc,
                          lds + PH2B(b) + ch * 1024 + lane * 16);
            }
        }
    };
    stage2(0, 0);
    stage2(1, 1);

    // ---- h0 panel -> LDS, relu+b0; cols [400,416)->0; >=416 dropped ----
#pragma unroll
    for (int i = 0; i < 2; ++i)
#pragma unroll
        for (int j = 0; j < NFRAG; ++j) {
            const int col = waveN * WCOLS + j * 16 + l16;
            if (col < HPAD) {
#pragma unroll
                for (int r = 0; r < 4; ++r) {
                    const int row = waveM * 32 + i * 16 + quad * 4 + r;
                    float v = acc[i][j][r] + b0;
                    v = v > 0.f ? v : 0.f;
                    if (col >= HDIM) v = 0.f;
                    h0p[row * H0S + col] = __float2bfloat16(v);
                }
            }
        }

    f32x4 acc2[2][NFRAG] = {};
    float w2v[NFRAG];
#pragma unroll
    for (int j = 0; j < NFRAG; ++j) {
        const int col = waveN * WCOLS + j * 16 + l16;
        w2v[j] = (col < HDIM) ? W2[col] : 0.f;
    }
    auto compute2 = [&](int p, int b) {
        const __hip_bfloat16* s = (const __hip_bfloat16*)(lds + PH2B(b));
        bf16x8 af[2], bfr[NFRAG];
#pragma unroll
        for (int i = 0; i < 2; ++i)
            af[i] = *(const bf16x8*)&h0p[(waveM * 32 + i * 16 + l16) * H0S + p * 32 + quad * 8];
#pragma unroll
        for (int j = 0; j < NFRAG; ++j)
            bfr[j] = *(const bf16x8*)&s[(waveN * NFRAG + j) * 512 + l16 * 32 + qsw];
        __builtin_amdgcn_s_setprio(1);
#pragma unroll
        for (int i = 0; i < 2; ++i)
#pragma unroll
            for (int j = 0; j < NFRAG; ++j)
                acc2[i][j] = __builtin_amdgcn_mfma_f32_16x16x32_bf16(
                    af[i], bfr[j], acc2[i][j], 0, 0, 0);
        __builtin_amdgcn_s_setprio(0);
    };

    // publish h0p (ds_writes) WITHOUT draining the in-flight stage2 DMA
    asm volatile("s_waitcnt lgkmcnt(0)" ::: "memory");
    bar();

    // ---- phase 2: 13 planes, 3-deep, ONE barrier per plane ----
    for (int p = 0; p < P2; ++p) {
        if (p + 1 < P2) { VMCNT(4); } else { VMCNT(0); }   // wave7: trivial
        bar();
        if (p + 2 < P2) stage2(p + 2, (p + 2) % 3);
        compute2(p, p % 3);
    }

    // ---- epilogue: relu(acc2+b1) . W2, lane reduce, cross-wave, sigmoid ----
#pragma unroll
    for (int i = 0; i < 2; ++i)
#pragma unroll
        for (int r = 0; r < 4; ++r) {
            float ps = 0.f;
#pragma unroll
            for (int j = 0; j < NFRAG; ++j) {
                float v = acc2[i][j][r] + b1;
                v = v > 0.f ? v : 0.f;
                ps += v * w2v[j];
            }
            ps += __shfl_xor(ps, 1); ps += __shfl_xor(ps, 2);
            ps += __shfl_xor(ps, 4); ps += __shfl_xor(ps, 8);
            if (l16 == 0)
                red[(waveM * 32 + i * 16 + quad * 4 + r) * 4 + waveN] = ps;
        }
    __syncthreads();

    if (tid < MROWS) {
        const float4 rr = *(const float4*)&red[tid * 4];
        const float s = (rr.x + rr.y) + (rr.z + rr.w);
        float hv = s + b2p[0];
        hv = hv > 0.f ? hv : 0.f;
        const float z = fs[m0 + tid] + hv;
        out[m0 + tid] = 1.f / (1.f + __expf(-z));
    }
}

extern "C" void kernel_launch(void* const* d_in, const int* in_sizes, int n_in,
                              void* d_out, int out_size, void* d_ws, size_t ws_size,
                              hipStream_t stream)
{
    const int*   feats     = (const int*)d_in[1];
    const float* values    = (const float*)d_in[2];
    const float* bias      = (const float*)d_in[3];
    const float* weights   = (const float*)d_in[4];
    const float* embedding = (const float*)d_in[5];
    const float* W0 = (const float*)d_in[6];
    const float* b0 = (const float*)d_in[7];
    const float* W1 = (const float*)d_in[8];
    const float* b1 = (const float*)d_in[9];
    const float* W2 = (const float*)d_in[10];
    const float* b2 = (const float*)d_in[11];

    char* ws = (char*)d_ws;
    size_t off = 0;
    auto alloc = [&](size_t bytes) {
        void* p = ws + off;
        off += (bytes + 255) & ~(size_t)255;
        return p;
    };
    float*          fs   = (float*)alloc((size_t)BATCH * 4);
    __hip_bfloat16* x    = (__hip_bfloat16*)alloc((size_t)BATCH * DDIM * 2);
    __hip_bfloat16* W0t  = (__hip_bfloat16*)alloc((size_t)NPAD * DDIM * 2);
    __hip_bfloat16* W1t  = (__hip_bfloat16*)alloc((size_t)NPAD * HPAD * 2);
    (void)ws_size; (void)in_sizes; (void)n_in; (void)out_size;

    prep_kernel<<<dim3(TBLK + GBLK), 256, 0, stream>>>(
        W0, W1, W0t, W1t, feats, values, bias, weights, embedding, fs, x);
    fused_mlp_kernel<<<dim3(BATCH / MROWS), 512, 0, stream>>>(
        x, W0t, W1t, b0, b1, W2, b2, fs, (float*)d_out);
}